// Round 13
// baseline (2108.028 us; speedup 1.0000x reference)
//
#include <hip/hip_runtime.h>
#include <stdint.h>

#define NB 64
#define NS 512
#define NI 512
#define NH 512

typedef __attribute__((ext_vector_type(8))) short bf16x8;
typedef __attribute__((ext_vector_type(4))) float f32x4;
typedef __attribute__((ext_vector_type(4))) unsigned u32x4;

__device__ __forceinline__ unsigned short f2bf(float f) {
  unsigned u = __float_as_uint(f);
  return (unsigned short)((u + 0x7fffu + ((u >> 16) & 1u)) >> 16);
}
__device__ __forceinline__ float bf2f(unsigned short h) {
  return __uint_as_float(((unsigned)h) << 16);
}
__device__ __forceinline__ float sigm(float x) { return 1.0f / (1.0f + __expf(-x)); }
__device__ __forceinline__ float tanh_f(float x) {
  float e = __expf(-2.0f * fabsf(x));
  return copysignf((1.0f - e) / (1.0f + e), x);
}

// ws layout (u32 units):
//  [0,512):   flags[8 groups][2 red-waves][32 slices] = steps published (monotonic)
//  [1024,+):  x_bf16 as u16[64][512][512]
#define FLAGS_OFF 0
#define XBF_OFF 1024
#define WS_BYTES_NEEDED ((size_t)XBF_OFF * 4 + (size_t)NB * NS * NI * 2)

__global__ __launch_bounds__(256) void k_xconv(const float* __restrict__ x,
                                               unsigned short* __restrict__ xb) {
  size_t i = ((size_t)blockIdx.x * 256 + threadIdx.x) * 4;
  float4 v = *(const float4*)(x + i);
  ushort4 o;
  o.x = f2bf(v.x); o.y = f2bf(v.y); o.z = f2bf(v.z); o.w = f2bf(v.w);
  *(ushort4*)(xb + i) = o;
}

__global__ __launch_bounds__(256) void k_init(unsigned int* __restrict__ ws) {
  int idx = blockIdx.x * 256 + threadIdx.x;
  if (idx < 512) ws[FLAGS_OFF + idx] = 0u;  // no steps published yet
}

// Persistent cooperative LSTM. grid 256 WGs x 512 thr. (R12 skeleton + fast poll)
// Group g = bid&7: 8 batches [g*8,+8). Slice s = bid>>3: h-cols [s*16,+16),
// all 4 gates. Wave w = K-eighth (cols [w*64,+64)).
// Per step: sentinel wave 7 polls the group's 64 flags FIRST via coalesced
// dwordx4 sc0|sc1 loads (16 lanes x 4 flags; R6-proven read primitive, tiny
// volume); raw S1 barrier releases the WG; every wave cached-loads its own h
// fragment from out(t-1) (per-step-unique addresses -> no stale-line hazard,
// proven R9/R11/R12); x-MFMA fills the load shadow; hi/lo bf16 split -> 12
// h-MFMAs -> part -> S2; reducer waves 0,1 publish fp32 h into `out` via sc1
// store + vmcnt ack + sc1 flag (R9-proven).
// WAR on single part buffer: rewritten only after S1(t+1); sentinel passes
// S1(t+1) only after all group flags(t+1), which require this WG's reducers
// to have finished reading part(t). Deadlock-free: flags(t+1) depend only on
// own-WG S2(t).
__global__ __launch_bounds__(512, 2) void k_lstm(
    const float* __restrict__ Wih, const float* __restrict__ bih,
    const float* __restrict__ Whh, const float* __restrict__ bhh,
    const float* __restrict__ h0, const float* __restrict__ c0,
    float* __restrict__ out, unsigned int* __restrict__ ws) {
  const int tid = threadIdx.x;
  const int lane = tid & 63;
  const int w = tid >> 6;   // K-eighth
  const int q = lane >> 4;
  const int c = lane & 15;
  const int b8 = lane & 7;  // A-frag batch (rows 8-15 duplicate 0-7)
  const int k0 = w * 64;
  const int g = blockIdx.x & 7;
  const int s = blockIdx.x >> 3;

  unsigned int* flagsG = ws + FLAGS_OFF + g * 64;  // [2 red-waves][32 slices]
  const unsigned short* xb = (const unsigned short*)(ws + XBF_OFF);

  // ---- weight fragments (hi/lo bf16 split): 4 gates x 2 K-chunks ----
  bf16x8 wih_hi[4][2], wih_lo[4][2], whh_hi[4][2], whh_lo[4][2];
#pragma unroll
  for (int g4 = 0; g4 < 4; ++g4) {
    const int wrow = g4 * 512 + s * 16 + c;  // B-frag col = c
#pragma unroll
    for (int kc = 0; kc < 2; ++kc) {
      const int kb = k0 + kc * 32 + q * 8;
      const float* pi = Wih + (size_t)wrow * NI + kb;
      const float* ph = Whh + (size_t)wrow * NH + kb;
      float4 i0 = *(const float4*)pi, i1 = *(const float4*)(pi + 4);
      float4 h0v = *(const float4*)ph, h1v = *(const float4*)(ph + 4);
      float vi[8] = {i0.x, i0.y, i0.z, i0.w, i1.x, i1.y, i1.z, i1.w};
      float vh[8] = {h0v.x, h0v.y, h0v.z, h0v.w, h1v.x, h1v.y, h1v.z, h1v.w};
#pragma unroll
      for (int r = 0; r < 8; ++r) {
        unsigned short a = f2bf(vi[r]);
        wih_hi[g4][kc][r] = (short)a;
        wih_lo[g4][kc][r] = (short)f2bf(vi[r] - bf2f(a));
        unsigned short b = f2bf(vh[r]);
        whh_hi[g4][kc][r] = (short)b;
        whh_lo[g4][kc][r] = (short)f2bf(vh[r] - bf2f(b));
      }
    }
  }

  // reducer mapping (waves 0,1): lane -> (batch bgc = g*8 + w*4 + q, col jg)
  const int bgc = g * 8 + ((w * 4 + q) & 7);  // clamped for non-reducer waves
  const int jg = s * 16 + c;
  const float bI = bih[jg] + bhh[jg];
  const float bF = bih[512 + jg] + bhh[512 + jg];
  const float bG = bih[1024 + jg] + bhh[1024 + jg];
  const float bO = bih[1536 + jg] + bhh[1536 + jg];
  float cst = c0[(size_t)bgc * NH + jg];

  __shared__ float part[4][8][4][72];  // [gate][wave][reg][col(+pad)]

  const unsigned short* xrow = xb + (size_t)(g * 8 + b8) * NS * NI + k0 + q * 8;
  bf16x8 xf0 = *(const bf16x8*)(xrow);
  bf16x8 xf1 = *(const bf16x8*)(xrow + 32);

  // sentinel poll pointer: 16 lanes x dwordx4 cover the 64 flags (4 lines)
  const unsigned* fp4 = flagsG + (lane & 15) * 4;

#pragma unroll 1
  for (int t = 0; t < NS; ++t) {
    // ---- sentinel wave 7: poll FIRST (coalesced cache-bypass dwordx4) ----
    if (w == 7 && t > 0) {
      const unsigned tgt = (unsigned)t;
      int ok;
      do {
        u32x4 f4;
        asm volatile("global_load_dwordx4 %0, %1, off sc0 sc1\n\ts_waitcnt vmcnt(0)"
                     : "=&v"(f4) : "v"(fp4) : "memory");
        ok = (lane < 16) ? (f4[0] >= tgt) & (f4[1] >= tgt) & (f4[2] >= tgt) & (f4[3] >= tgt) : 1;
      } while (!__all(ok));
    }

    // ---- non-sentinel waves: x-path MFMA before S1 (runs during the poll) ----
    f32x4 acc[4];
#pragma unroll
    for (int g4 = 0; g4 < 4; ++g4) acc[g4] = (f32x4){0.f, 0.f, 0.f, 0.f};
    if (w != 7) {
#pragma unroll
      for (int g4 = 0; g4 < 4; ++g4) {
        acc[g4] = __builtin_amdgcn_mfma_f32_16x16x32_bf16(xf0, wih_hi[g4][0], acc[g4], 0, 0, 0);
        acc[g4] = __builtin_amdgcn_mfma_f32_16x16x32_bf16(xf0, wih_lo[g4][0], acc[g4], 0, 0, 0);
        acc[g4] = __builtin_amdgcn_mfma_f32_16x16x32_bf16(xf1, wih_hi[g4][1], acc[g4], 0, 0, 0);
        acc[g4] = __builtin_amdgcn_mfma_f32_16x16x32_bf16(xf1, wih_lo[g4][1], acc[g4], 0, 0, 0);
      }
    }
    asm volatile("" ::: "memory");
    __builtin_amdgcn_s_barrier();  // S1: h(t-1) fully published
    asm volatile("" ::: "memory");

    // ---- all waves: issue h fragment loads (RT hidden by following MFMAs) ----
    float4 hA0, hB0, hA1, hB1;
    {
      const float* hr = (t == 0)
          ? (h0 + (size_t)(g * 8 + b8) * NH + k0 + q * 8)
          : (out + ((size_t)(g * 8 + b8) * NS + (t - 1)) * NH + k0 + q * 8);
      hA0 = *(const float4*)hr;
      hB0 = *(const float4*)(hr + 4);
      hA1 = *(const float4*)(hr + 32);
      hB1 = *(const float4*)(hr + 36);
    }

    // ---- sentinel: x-path MFMA now (fills its h-load shadow) ----
    if (w == 7) {
#pragma unroll
      for (int g4 = 0; g4 < 4; ++g4) {
        acc[g4] = __builtin_amdgcn_mfma_f32_16x16x32_bf16(xf0, wih_hi[g4][0], acc[g4], 0, 0, 0);
        acc[g4] = __builtin_amdgcn_mfma_f32_16x16x32_bf16(xf0, wih_lo[g4][0], acc[g4], 0, 0, 0);
        acc[g4] = __builtin_amdgcn_mfma_f32_16x16x32_bf16(xf1, wih_hi[g4][1], acc[g4], 0, 0, 0);
        acc[g4] = __builtin_amdgcn_mfma_f32_16x16x32_bf16(xf1, wih_lo[g4][1], acc[g4], 0, 0, 0);
      }
    }

    // ---- h-path: fp32 -> hi/lo bf16 -> 3-term MFMA ----
#pragma unroll
    for (int kc = 0; kc < 2; ++kc) {
      float hv8[8];
      if (kc == 0) {
        hv8[0] = hA0.x; hv8[1] = hA0.y; hv8[2] = hA0.z; hv8[3] = hA0.w;
        hv8[4] = hB0.x; hv8[5] = hB0.y; hv8[6] = hB0.z; hv8[7] = hB0.w;
      } else {
        hv8[0] = hA1.x; hv8[1] = hA1.y; hv8[2] = hA1.z; hv8[3] = hA1.w;
        hv8[4] = hB1.x; hv8[5] = hB1.y; hv8[6] = hB1.z; hv8[7] = hB1.w;
      }
      bf16x8 hh, hl;
#pragma unroll
      for (int r = 0; r < 8; ++r) {
        unsigned short a = f2bf(hv8[r]);
        hh[r] = (short)a;
        hl[r] = (short)f2bf(hv8[r] - bf2f(a));
      }
#pragma unroll
      for (int g4 = 0; g4 < 4; ++g4) {
        acc[g4] = __builtin_amdgcn_mfma_f32_16x16x32_bf16(hh, whh_hi[g4][kc], acc[g4], 0, 0, 0);
        acc[g4] = __builtin_amdgcn_mfma_f32_16x16x32_bf16(hl, whh_hi[g4][kc], acc[g4], 0, 0, 0);
        acc[g4] = __builtin_amdgcn_mfma_f32_16x16x32_bf16(hh, whh_lo[g4][kc], acc[g4], 0, 0, 0);
      }
    }

#pragma unroll
    for (int g4 = 0; g4 < 4; ++g4)
#pragma unroll
      for (int r = 0; r < 4; ++r) part[g4][w][r][lane] = acc[g4][r];

    const int tn = (t + 1 < NS) ? t + 1 : t;
    if (w >= 2) {  // non-reducers: x prefetch before S2 (issue early, hidden)
      xf0 = *(const bf16x8*)(xrow + (size_t)tn * NI);
      xf1 = *(const bf16x8*)(xrow + (size_t)tn * NI + 32);
    }

    asm volatile("s_waitcnt lgkmcnt(0)" ::: "memory");
    __builtin_amdgcn_s_barrier();  // S2: part visible to reducers
    asm volatile("" ::: "memory");

    if (w < 2) {  // reducers: lane owns (b = w*4+q, j = c)
      float sI = bI, sF = bF, sG = bG, sO = bO;
      const int cidx = w * 16 + c;
#pragma unroll
      for (int ww = 0; ww < 8; ++ww) {
        sI += part[0][ww][q][cidx];
        sF += part[1][ww][q][cidx];
        sG += part[2][ww][q][cidx];
        sO += part[3][ww][q][cidx];
      }
      float cn = sigm(sF) * cst + sigm(sI) * tanh_f(sG);
      cst = cn;
      float hv = sigm(sO) * tanh_f(cn);

      // publish: sc1 store of hv into out (the output store IS the exchange)
      unsigned* dst = (unsigned*)out + ((size_t)bgc * NS + t) * NH + jg;
      __hip_atomic_store(dst, __float_as_uint(hv), __ATOMIC_RELAXED, __HIP_MEMORY_SCOPE_AGENT);
      asm volatile("s_waitcnt vmcnt(0)" ::: "memory");  // data at coherence point
      if (lane == 0)
        __hip_atomic_store(flagsG + w * 32 + s, (unsigned)(t + 1),
                           __ATOMIC_RELAXED, __HIP_MEMORY_SCOPE_AGENT);

      if (t == NS - 1) {  // final h/c tail (plain; flushed at kernel end)
        size_t hoff = (size_t)NB * NS * NH;
        out[hoff + (size_t)bgc * NH + jg] = hv;
        out[hoff + (size_t)NB * NH + (size_t)bgc * NH + jg] = cn;
      }
      // reducer x prefetch after the ack (so vmcnt(0) saw only the hv store)
      xf0 = *(const bf16x8*)(xrow + (size_t)tn * NI);
      xf1 = *(const bf16x8*)(xrow + (size_t)tn * NI + 32);
    }
  }
}

extern "C" void kernel_launch(void* const* d_in, const int* in_sizes, int n_in,
                              void* d_out, int out_size, void* d_ws, size_t ws_size,
                              hipStream_t stream) {
  if (ws_size < WS_BYTES_NEEDED) return;  // fail visibly rather than corrupt

  const float* x   = (const float*)d_in[0];
  const float* h0  = (const float*)d_in[1];
  const float* c0  = (const float*)d_in[2];
  const float* Wih = (const float*)d_in[3];
  const float* bih = (const float*)d_in[4];
  const float* Whh = (const float*)d_in[5];
  const float* bhh = (const float*)d_in[6];
  float* out = (float*)d_out;
  unsigned int* ws = (unsigned int*)d_ws;
  unsigned short* xbptr = (unsigned short*)(ws + XBF_OFF);

  k_xconv<<<dim3(16384), dim3(256), 0, stream>>>(x, xbptr);
  k_init<<<dim3(2), dim3(256), 0, stream>>>(ws);

  void* args[] = {(void*)&Wih, (void*)&bih, (void*)&Whh, (void*)&bhh,
                  (void*)&h0,  (void*)&c0,  (void*)&out, (void*)&ws};
  hipLaunchCooperativeKernel((const void*)k_lstm, dim3(256), dim3(512), args, 0, stream);
}